// Round 1
// 713.189 us; speedup vs baseline: 1.4372x; 1.4372x over previous
//
#include <hip/hip_runtime.h>
#include <hip/hip_bf16.h>
#include <math.h>

#define BATCH 4
#define NHEADS 16
#define SEQ 2048
#define HDIM 128
#define NPAT 4

#define BM 128
#define BN 64
#define NTHREADS 256
#define NKT (SEQ / BN)          // 32 kv-tiles per (b,h)
#define TILE_BYTES 16384        // K tile: 64 rows x 256B ; V^T tile: 128 rows x 128B
#define NBLOCKS (BATCH * NHEADS * (SEQ / BM))   // 1024

typedef _Float16 f16x8 __attribute__((ext_vector_type(8)));
typedef float floatx4 __attribute__((ext_vector_type(4)));

typedef const __attribute__((address_space(1))) void gvoid_t;
typedef __attribute__((address_space(3))) void lvoid_t;

// ---------------- selector: per-head pattern argmax ----------------
__global__ void sel_kernel(const float* __restrict__ w1, const float* __restrict__ b1,
                           const float* __restrict__ w2, const float* __restrict__ b2,
                           int* __restrict__ pat_idx) {
  int h = threadIdx.x;
  if (h >= NHEADS) return;
  float f0 = 1.0f;               // S / MAX_SEQ_LEN = 2048/2048
  float f1 = (float)h / 12.0f;
  float f2 = 0.5f;
  float acc[NPAT] = {b2[0], b2[1], b2[2], b2[3]};
  for (int j = 0; j < 32; ++j) {
    float hj = f0 * w1[j] + f1 * w1[32 + j] + f2 * w1[64 + j] + b1[j];
    hj = fmaxf(hj, 0.0f);
    for (int p = 0; p < NPAT; ++p) acc[p] += hj * w2[j * NPAT + p];
  }
  int best = 0;
  float bv = acc[0];
  for (int p = 1; p < NPAT; ++p) {
    if (acc[p] > bv) { bv = acc[p]; best = p; }   // strict > : first-max like jnp.argmax
  }
  pat_idx[h] = best;
}

// ---------------- binarize pattern masks to bit words ----------------
// Reference does sigmoid(x) > 0.5 IN FP32. For 0 < x <~ 1.5*2^-24, fp32
// sigmoid rounds to exactly 0.5 -> mask 0, unlike mathematical x>0.
// Exact emulation (double exp) only needed in a tiny window around 0:
// for |x| >= 1e-5 the fp32-rounded sigmoid compares against 0.5 exactly
// like sign(x) (error bound ~1 ulp at 0.5 = 6e-8 << 2.5e-6 margin).
__device__ __forceinline__ bool sig_gt_half(float x) {
  float t = (float)exp(-(double)x);   // correctly-rounded fp32 exp(-x)
  float s = 1.0f / (1.0f + t);        // fp32 IEEE add + div
  return s > 0.5f;
}

__global__ void bin_kernel(const float* __restrict__ pm, unsigned int* __restrict__ bits) {
  int t = blockIdx.x * blockDim.x + threadIdx.x;  // one 32-col word per thread
  const float4* s4 = (const float4*)(pm + (size_t)t * 32);
  unsigned int w = 0;
#pragma unroll
  for (int i = 0; i < 8; ++i) {
    float4 v = s4[i];
    float e[4] = {v.x, v.y, v.z, v.w};
#pragma unroll
    for (int j = 0; j < 4; ++j) {
      bool b;
      if (fabsf(e[j]) < 1e-5f) b = sig_gt_half(e[j]);  // rare exact-rounding window
      else                     b = (e[j] > 0.0f);      // fast sign path
      w |= (b ? 1u : 0u) << (i * 4 + j);
    }
  }
  bits[t] = w;
}

// ---------------- preprocess K: fp32 -> fp16 swizzled tiles ----------------
// Kp tile layout (16KB per (bh,kt)): byte o holds K[tile*64 + r][c] fp16 where
// r = o>>8, c = ((o&255) ^ ((r&7)<<4)) >> 1.  flash stages this linearly via
// global_load_lds and reads fragments at byte r*256 + (colbyte ^ ((r&7)<<4))
// -> conflict-free ds_read_b128 (rows spread over 8 distinct 16B slots).
__global__ __launch_bounds__(256) void prep_k(const float* __restrict__ K,
                                              _Float16* __restrict__ Kp) {
  size_t q0 = ((size_t)blockIdx.x * 256 + threadIdx.x) * 16;  // output byte
  int tile = (int)(q0 >> 14);
  int p = (int)(q0 & 16383);
  int r = p >> 8;
  int cb = (p & 255) ^ ((r & 7) << 4);
  const float* src = K + ((size_t)tile * 64 + r) * HDIM + (cb >> 1);
  float4 a = ((const float4*)src)[0];
  float4 b = ((const float4*)src)[1];
  f16x8 f;
  f[0] = (_Float16)a.x; f[1] = (_Float16)a.y; f[2] = (_Float16)a.z; f[3] = (_Float16)a.w;
  f[4] = (_Float16)b.x; f[5] = (_Float16)b.y; f[6] = (_Float16)b.z; f[7] = (_Float16)b.w;
  *(f16x8*)((char*)Kp + q0) = f;
}

// ---------------- preprocess V: fp32 -> fp16 transposed swizzled tiles ------
// Vt tile (16KB per (bh,kt)) = V^T [d=128][kc=64] fp16, byte o holds
// V[tile*64 + kc][d] with d = o>>7, kc = ((o&127) ^ ((d&7)<<4)) >> 1.
// Reads are strided (column gather) but each wave instruction touches 8 rows
// x 32B within 64B lines whose other half is consumed by the adjacent wave
// of the same block -> L1 absorbs the 2x. One-shot pass, HBM-bound.
__global__ __launch_bounds__(256) void prep_vt(const float* __restrict__ V,
                                               _Float16* __restrict__ Vt) {
  int tile = blockIdx.x;
  const float* vsrc = V + (size_t)tile * 64 * HDIM;
  char* dst = (char*)Vt + (size_t)tile * TILE_BYTES;
#pragma unroll
  for (int i = 0; i < 4; ++i) {
    int p = (i * 256 + (int)threadIdx.x) * 16;   // output byte in tile
    int d = p >> 7;
    int kc0 = ((p & 127) ^ ((d & 7) << 4)) >> 1;
    f16x8 f;
#pragma unroll
    for (int j = 0; j < 8; ++j) f[j] = (_Float16)vsrc[(size_t)(kc0 + j) * HDIM + d];
    *(f16x8*)(dst + p) = f;
  }
}

// ---------------- flash attention with multiplicative binary mask ----------------
// Grid: 1024 blocks (XCD chunk-swizzled), 256 threads (4 waves), wave owns 32 q-rows.
// K and V^T arrive as preprocessed fp16 swizzled tiles -> staged with
// global_load_lds width=16 (no VGPR roundtrip, no cvt, no ds_write conflicts).
// LDS 52224 B -> 3 blocks/CU. Numerics identical to previous version.
__global__ __launch_bounds__(NTHREADS, 3) void flash_kernel(
    const float* __restrict__ Q, const _Float16* __restrict__ Kp,
    const _Float16* __restrict__ Vt, const unsigned int* __restrict__ bits,
    const int* __restrict__ pat_idx, float* __restrict__ out) {
  __shared__ alignas(16) char kv_raw[2 * TILE_BYTES];     // K tile @0, V^T tile @16384
  __shared__ alignas(16) _Float16 p_lds[4][32][BN + 8];   // per-wave P C->A transform
  __shared__ unsigned int maskw[BM][2];

  const int tid = threadIdx.x;
  const int wave = tid >> 6;
  const int lane = tid & 63;
  const int l16 = lane & 15;
  const int quad = lane >> 4;
  const int swz = l16 & 7;

  // bijective XCD chunk swizzle: XCD x gets logical blocks [x*128, x*128+128)
  // -> all 16 q-tiles of 8 consecutive (b,h) share one XCD's L2 for K/V tiles
  int bid = (int)blockIdx.x;
  bid = (bid & 7) * (NBLOCKS / 8) + (bid >> 3);
  const int bh = bid >> 4;       // 0..63 = b*16+h
  const int qt = bid & 15;
  const int h = bh & (NHEADS - 1);
  const int qbase = qt * BM;
  const int pat = pat_idx[h];

  // (1/sqrt(128)) * log2(e): softmax in base 2; masked entries -> score exactly 0
  const float SCL = 0.08838834764831845f * 1.4426950408889634f;
  const float P_MIN = 6.103515625e-05f;  // 2^-14: fp16 normal floor; below -> 0

  // Q fragments, A-layout: A[m=lane&15][k=quad*8+j], registers for whole kernel
  f16x8 qf[2][4];
#pragma unroll
  for (int mt = 0; mt < 2; ++mt) {
    const int row = qbase + wave * 32 + mt * 16 + l16;
    const float* qp = Q + ((size_t)bh * SEQ + row) * HDIM;
#pragma unroll
    for (int ks = 0; ks < 4; ++ks) {
      const float4* p4 = (const float4*)(qp + ks * 32 + quad * 8);
      float4 a = p4[0], c = p4[1];
      f16x8 f;
      f[0] = (_Float16)a.x; f[1] = (_Float16)a.y; f[2] = (_Float16)a.z; f[3] = (_Float16)a.w;
      f[4] = (_Float16)c.x; f[5] = (_Float16)c.y; f[6] = (_Float16)c.z; f[7] = (_Float16)c.w;
      qf[mt][ks] = f;
    }
  }

  floatx4 o_acc[2][8];
#pragma unroll
  for (int mt = 0; mt < 2; ++mt)
#pragma unroll
    for (int n = 0; n < 8; ++n) o_acc[mt][n] = (floatx4){0.f, 0.f, 0.f, 0.f};
  float m_run[2][4], l_run[2][4];
#pragma unroll
  for (int mt = 0; mt < 2; ++mt)
#pragma unroll
    for (int r = 0; r < 4; ++r) { m_run[mt][r] = -INFINITY; l_run[mt][r] = 0.0f; }

  const char* kg = (const char*)Kp + (size_t)bh * NKT * TILE_BYTES;
  const char* vg = (const char*)Vt + (size_t)bh * NKT * TILE_BYTES;
  const unsigned int* bits_p = bits + ((size_t)pat * SEQ + qbase) * (SEQ / 32);

  for (int kt = 0; kt < NKT; ++kt) {
    __syncthreads();  // previous iter's LDS reads done before restage
    {
      // async global->LDS staging: per wave 4x1KB for K, 4x1KB for V^T.
      // LDS dest = wave-uniform base + lane*16 (linear); swizzle is already
      // baked into the global tile layout by prep_k/prep_vt.
      const char* kgt = kg + (size_t)kt * TILE_BYTES + wave * 1024 + lane * 16;
      const char* vgt = vg + (size_t)kt * TILE_BYTES + wave * 1024 + lane * 16;
      char* kl = kv_raw + wave * 1024;
      char* vl = kv_raw + TILE_BYTES + wave * 1024;
#pragma unroll
      for (int i = 0; i < 4; ++i) {
        __builtin_amdgcn_global_load_lds((gvoid_t*)(kgt + i * 4096),
                                         (lvoid_t*)(kl + i * 4096), 16, 0, 0);
        __builtin_amdgcn_global_load_lds((gvoid_t*)(vgt + i * 4096),
                                         (lvoid_t*)(vl + i * 4096), 16, 0, 0);
      }
      int mr = tid >> 1, mw = tid & 1;
      maskw[mr][mw] = bits_p[(size_t)mr * (SEQ / 32) + kt * 2 + mw];
    }
    __syncthreads();  // compiler drains vmcnt+lgkmcnt before s_barrier

    // ---- S = Q @ K^T ---- (B fragment: row r = nt*16+l16, swizzled slot read)
    floatx4 sf[2][4];
#pragma unroll
    for (int mt = 0; mt < 2; ++mt)
#pragma unroll
      for (int nt = 0; nt < 4; ++nt) sf[mt][nt] = (floatx4){0.f, 0.f, 0.f, 0.f};
    __builtin_amdgcn_s_setprio(1);
#pragma unroll
    for (int nt = 0; nt < 4; ++nt) {
      const char* krow = kv_raw + ((nt * 16 + l16) << 8);
#pragma unroll
      for (int ks = 0; ks < 4; ++ks) {
        f16x8 bf = *(const f16x8*)(krow + ((((ks << 2) | quad) ^ swz) << 4));
#pragma unroll
        for (int mt = 0; mt < 2; ++mt)
          sf[mt][nt] = __builtin_amdgcn_mfma_f32_16x16x32_f16(qf[mt][ks], bf, sf[mt][nt], 0, 0, 0);
      }
    }
    __builtin_amdgcn_s_setprio(0);

    // ---- mask (multiplicative!) + online softmax (base 2) ----
    float alpha[2][4];
#pragma unroll
    for (int mt = 0; mt < 2; ++mt) {
#pragma unroll
      for (int r = 0; r < 4; ++r) {
        int rl = wave * 32 + mt * 16 + quad * 4 + r;   // C-layout row
        unsigned int w0 = maskw[rl][0], w1 = maskw[rl][1];
#pragma unroll
        for (int nt = 0; nt < 4; ++nt) {
          unsigned int wd = (nt & 2) ? w1 : w0;
          int bit = ((nt & 1) << 4) | l16;             // C-layout col = nt*16 + l16
          float s = sf[mt][nt][r];
          sf[mt][nt][r] = ((wd >> bit) & 1u) ? s * SCL : 0.0f;  // masked -> score exactly 0
        }
        float mx = fmaxf(fmaxf(sf[mt][0][r], sf[mt][1][r]), fmaxf(sf[mt][2][r], sf[mt][3][r]));
        mx = fmaxf(mx, __shfl_xor(mx, 1));
        mx = fmaxf(mx, __shfl_xor(mx, 2));
        mx = fmaxf(mx, __shfl_xor(mx, 4));
        mx = fmaxf(mx, __shfl_xor(mx, 8));
        float m_old = m_run[mt][r];
        float m_new = fmaxf(m_old, mx);
        float a = exp2f(m_old - m_new);                // first iter: exp2(-inf)=0
        alpha[mt][r] = a;
        m_run[mt][r] = m_new;
        float ps = 0.0f;
#pragma unroll
        for (int nt = 0; nt < 4; ++nt) {
          float p = exp2f(sf[mt][nt][r] - m_new);      // masked entries contribute 2^(0-m)
          if (p < P_MIN) p = 0.0f;                     // stay out of fp16 subnormals
          float pqf = (float)(_Float16)p;              // quantize FIRST...
          sf[mt][nt][r] = pqf;
          ps += pqf;                                   // ...then sum: l matches MFMA weights
        }
        ps += __shfl_xor(ps, 1);
        ps += __shfl_xor(ps, 2);
        ps += __shfl_xor(ps, 4);
        ps += __shfl_xor(ps, 8);
        l_run[mt][r] = l_run[mt][r] * a + ps;
      }
    }

    // ---- rescale O ----
#pragma unroll
    for (int mt = 0; mt < 2; ++mt)
#pragma unroll
      for (int n = 0; n < 8; ++n)
#pragma unroll
        for (int r = 0; r < 4; ++r) o_acc[mt][n][r] *= alpha[mt][r];

    // ---- P: C-layout -> A-layout via per-wave LDS (m120-verified transform) ----
#pragma unroll
    for (int mt = 0; mt < 2; ++mt)
#pragma unroll
      for (int nt = 0; nt < 4; ++nt)
#pragma unroll
        for (int r = 0; r < 4; ++r)
          p_lds[wave][mt * 16 + quad * 4 + r][nt * 16 + l16] = (_Float16)sf[mt][nt][r];
    // per-wave region: compiler inserts lgkmcnt waits

    // ---- O += P @ V ---- (B fragment: row d = nt*16+l16, swizzled slot read)
    __builtin_amdgcn_s_setprio(1);
#pragma unroll
    for (int ks = 0; ks < 2; ++ks) {
      f16x8 pa[2];
#pragma unroll
      for (int mt = 0; mt < 2; ++mt)
        pa[mt] = *(const f16x8*)&p_lds[wave][mt * 16 + l16][ks * 32 + quad * 8];
#pragma unroll
      for (int nt = 0; nt < 8; ++nt) {
        const char* vrow = kv_raw + TILE_BYTES + ((nt * 16 + l16) << 7);
        f16x8 vb = *(const f16x8*)(vrow + ((((ks << 2) | quad) ^ swz) << 4));
#pragma unroll
        for (int mt = 0; mt < 2; ++mt)
          o_acc[mt][nt] = __builtin_amdgcn_mfma_f32_16x16x32_f16(pa[mt], vb, o_acc[mt][nt], 0, 0, 0);
      }
    }
    __builtin_amdgcn_s_setprio(0);
  }

  // ---- epilogue: O / l ----
#pragma unroll
  for (int mt = 0; mt < 2; ++mt) {
#pragma unroll
    for (int r = 0; r < 4; ++r) {
      const float inv = 1.0f / l_run[mt][r];
      const int row = qbase + wave * 32 + mt * 16 + quad * 4 + r;
      float* og = out + ((size_t)bh * SEQ + row) * HDIM + l16;
#pragma unroll
      for (int n = 0; n < 8; ++n) og[n * 16] = o_acc[mt][n][r] * inv;
    }
  }
}

extern "C" void kernel_launch(void* const* d_in, const int* in_sizes, int n_in,
                              void* d_out, int out_size, void* d_ws, size_t ws_size,
                              hipStream_t stream) {
  const float* Q  = (const float*)d_in[0];
  const float* K  = (const float*)d_in[1];
  const float* V  = (const float*)d_in[2];
  const float* pm = (const float*)d_in[3];
  const float* w1 = (const float*)d_in[4];
  const float* b1 = (const float*)d_in[5];
  const float* w2 = (const float*)d_in[6];
  const float* b2 = (const float*)d_in[7];
  float* out = (float*)d_out;

  // workspace layout (all 16B-aligned):
  //   [0,4096)                      pat_idx
  //   [4096, 4096+2MB)              mask bit words (4 pats x 2048 x 64 words)
  //   [+0, +32MB)                   Kp fp16 swizzled tiles (64 bh x 32 kt x 16KB)
  //   [+32MB, +64MB)                Vt fp16 transposed swizzled tiles
  int* pat_idx = (int*)d_ws;
  unsigned int* bits = (unsigned int*)((char*)d_ws + 4096);
  _Float16* Kp = (_Float16*)((char*)d_ws + 4096 + 2097152);
  _Float16* Vt = (_Float16*)((char*)d_ws + 4096 + 2097152 + 33554432);

  sel_kernel<<<1, 64, 0, stream>>>(w1, b1, w2, b2, pat_idx);
  bin_kernel<<<(NPAT * SEQ * (SEQ / 32)) / 256, 256, 0, stream>>>(pm, bits);
  prep_k<<<(BATCH * NHEADS * NKT * 1024) / 256, 256, 0, stream>>>(K, Kp);
  prep_vt<<<BATCH * NHEADS * NKT, 256, 0, stream>>>(V, Vt);
  flash_kernel<<<NBLOCKS, NTHREADS, 0, stream>>>(Q, Kp, Vt, bits, pat_idx, out);
}

// Round 2
// 525.736 us; speedup vs baseline: 1.9497x; 1.3566x over previous
//
#include <hip/hip_runtime.h>
#include <hip/hip_bf16.h>
#include <math.h>

#define BATCH 4
#define NHEADS 16
#define SEQ 2048
#define HDIM 128
#define NPAT 4

#define BM 128
#define BN 64
#define NTHREADS 256
#define NKT (SEQ / BN)          // 32 kv-tiles per (b,h)
#define TILE_BYTES 16384        // K tile: 64 rows x 256B ; V^T tile: 128 rows x 128B
#define NBLOCKS (BATCH * NHEADS * (SEQ / BM))   // 1024

typedef _Float16 f16x8 __attribute__((ext_vector_type(8)));
typedef _Float16 f16x4 __attribute__((ext_vector_type(4)));
typedef float floatx4 __attribute__((ext_vector_type(4)));

typedef const __attribute__((address_space(1))) void gvoid_t;
typedef __attribute__((address_space(3))) void lvoid_t;

// ---------------- selector: per-head pattern argmax (+ used-pattern flags) ----
__global__ void sel_kernel(const float* __restrict__ w1, const float* __restrict__ b1,
                           const float* __restrict__ w2, const float* __restrict__ b2,
                           int* __restrict__ pat_idx, int* __restrict__ used) {
  int h = threadIdx.x;
  if (h < NPAT) used[h] = 0;
  __syncthreads();
  if (h >= NHEADS) return;
  float f0 = 1.0f;               // S / MAX_SEQ_LEN = 2048/2048
  float f1 = (float)h / 12.0f;
  float f2 = 0.5f;
  float acc[NPAT] = {b2[0], b2[1], b2[2], b2[3]};
  for (int j = 0; j < 32; ++j) {
    float hj = f0 * w1[j] + f1 * w1[32 + j] + f2 * w1[64 + j] + b1[j];
    hj = fmaxf(hj, 0.0f);
    for (int p = 0; p < NPAT; ++p) acc[p] += hj * w2[j * NPAT + p];
  }
  int best = 0;
  float bv = acc[0];
  for (int p = 1; p < NPAT; ++p) {
    if (acc[p] > bv) { bv = acc[p]; best = p; }   // strict > : first-max like jnp.argmax
  }
  pat_idx[h] = best;
  atomicOr(&used[best], 1);
}

// ---------------- binarize pattern masks to bit words ----------------
// Reference does sigmoid(x) > 0.5 IN FP32. Exact emulation (double exp) only
// needed in a tiny window around 0; |x|>=1e-5 compares like sign(x).
// Patterns not selected by any head are skipped entirely.
__device__ __forceinline__ bool sig_gt_half(float x) {
  float t = (float)exp(-(double)x);   // correctly-rounded fp32 exp(-x)
  float s = 1.0f / (1.0f + t);        // fp32 IEEE add + div
  return s > 0.5f;
}

__global__ void bin_kernel(const float* __restrict__ pm, unsigned int* __restrict__ bits,
                           const int* __restrict__ used) {
  int pat = blockIdx.x >> 9;                      // 512 blocks per pattern
  if (!used[pat]) return;
  int t = blockIdx.x * blockDim.x + threadIdx.x;  // one 32-col word per thread
  const float4* s4 = (const float4*)(pm + (size_t)t * 32);
  unsigned int w = 0;
#pragma unroll
  for (int i = 0; i < 8; ++i) {
    float4 v = s4[i];
    float e[4] = {v.x, v.y, v.z, v.w};
#pragma unroll
    for (int j = 0; j < 4; ++j) {
      bool b;
      if (fabsf(e[j]) < 1e-5f) b = sig_gt_half(e[j]);  // rare exact-rounding window
      else                     b = (e[j] > 0.0f);      // fast sign path
      w |= (b ? 1u : 0u) << (i * 4 + j);
    }
  }
  bits[t] = w;
}

// ---------------- preprocess K: fp32 -> fp16 swizzled tiles ----------------
// Kp tile layout (16KB per (bh,kt)): byte o holds K[tile*64 + r][c] fp16 where
// r = o>>8, c = ((o&255) ^ ((r&7)<<4)) >> 1.  flash stages this linearly via
// global_load_lds and reads fragments at byte r*256 + (colbyte ^ ((r&7)<<4))
// -> conflict-free ds_read_b128.
__global__ __launch_bounds__(256) void prep_k(const float* __restrict__ K,
                                              _Float16* __restrict__ Kp) {
  size_t q0 = ((size_t)blockIdx.x * 256 + threadIdx.x) * 16;  // output byte
  int tile = (int)(q0 >> 14);
  int p = (int)(q0 & 16383);
  int r = p >> 8;
  int cb = (p & 255) ^ ((r & 7) << 4);
  const float* src = K + ((size_t)tile * 64 + r) * HDIM + (cb >> 1);
  float4 a = ((const float4*)src)[0];
  float4 b = ((const float4*)src)[1];
  f16x8 f;
  f[0] = (_Float16)a.x; f[1] = (_Float16)a.y; f[2] = (_Float16)a.z; f[3] = (_Float16)a.w;
  f[4] = (_Float16)b.x; f[5] = (_Float16)b.y; f[6] = (_Float16)b.z; f[7] = (_Float16)b.w;
  *(f16x8*)((char*)Kp + q0) = f;
}

// ---------------- preprocess V: LDS-transposed fp16 tiles -------------------
// Vt tile (16KB per (bh,kt)) = V^T [d=128][kc-slot], both sides coalesced via
// an LDS tile transpose. kc-slot ordering bakes BOTH the XOR-16B swizzle and
// the in-register P-exchange permutation used by flash's PV step:
//   chunk c' at row d holds logical chunk clog = c' ^ (d&7); q=clog&3, ks=clog>>2
//   slot j in chunk -> kc = ((q>>1)*2+ks)*16 + (j<4 ? q : q^2)*4 + (j&3)
__global__ __launch_bounds__(256) void prep_vt(const float* __restrict__ V,
                                               _Float16* __restrict__ Vt) {
  __shared__ _Float16 tile[64][140];   // pitch 140 f16 = 280B (8B-aligned, bank-spread)
  const int t = threadIdx.x;
  const float* vsrc = V + (size_t)blockIdx.x * 64 * HDIM;
#pragma unroll
  for (int i = 0; i < 8; ++i) {
    int idx = i * 256 + t;             // 2048 float4 chunks: row kc, 32 chunks/row
    int kc = idx >> 5, c4 = idx & 31;
    float4 v = ((const float4*)(vsrc + kc * HDIM))[c4];
    f16x4 f;
    f[0] = (_Float16)v.x; f[1] = (_Float16)v.y; f[2] = (_Float16)v.z; f[3] = (_Float16)v.w;
    *(f16x4*)&tile[kc][c4 * 4] = f;
  }
  __syncthreads();
  char* dst = (char*)Vt + (size_t)blockIdx.x * TILE_BYTES;
#pragma unroll
  for (int i = 0; i < 4; ++i) {
    int p = (i * 256 + t) * 16;        // output byte in tile
    int d = p >> 7;
    int cp = (p & 127) >> 4;
    int clog = cp ^ (d & 7);
    int q = clog & 3, ks = clog >> 2;
    int T16 = ((q >> 1) * 2 + ks) << 4;
    f16x8 f;
#pragma unroll
    for (int j = 0; j < 8; ++j) {
      int qsel = (j < 4) ? q : (q ^ 2);
      int kc = T16 + qsel * 4 + (j & 3);
      f[j] = tile[kc][d];
    }
    *(f16x8*)(dst + p) = f;
  }
}

// ---------------- flash attention with multiplicative binary mask ----------------
// Swapped QK^T (mfma(K,Q) -> S^T): lane l16 = qrow, so softmax reduces are
// 15 local ops + 2 shuffles, and P goes C->A in-register via packed
// __shfl_xor(32) (permutation baked into prep_vt's kc-slot order). No p_lds:
// LDS = 33792 B -> 3 blocks/CU with __launch_bounds__(256,3).
__global__ __launch_bounds__(NTHREADS, 3) void flash_kernel(
    const float* __restrict__ Q, const _Float16* __restrict__ Kp,
    const _Float16* __restrict__ Vt, const unsigned int* __restrict__ bits,
    const int* __restrict__ pat_idx, float* __restrict__ out) {
  __shared__ alignas(16) char kv_raw[2 * TILE_BYTES];     // K tile @0, V^T tile @16384
  __shared__ unsigned int maskw[BM][2];

  const int tid = threadIdx.x;
  const int wave = tid >> 6;
  const int lane = tid & 63;
  const int l16 = lane & 15;
  const int quad = lane >> 4;
  const int swz = l16 & 7;

  // bijective XCD chunk swizzle
  int bid = (int)blockIdx.x;
  bid = (bid & 7) * (NBLOCKS / 8) + (bid >> 3);
  const int bh = bid >> 4;       // 0..63 = b*16+h
  const int qt = bid & 15;
  const int h = bh & (NHEADS - 1);
  const int qbase = qt * BM;
  const int pat = pat_idx[h];

  const float SCL = 0.08838834764831845f * 1.4426950408889634f;  // rsqrt(128)*log2(e)
  const float P_MIN = 6.103515625e-05f;  // 2^-14: fp16 normal floor; below -> 0

  // Q fragments: B-operand of swapped QK^T, B[k=quad*8+j (d)][n=l16 (qrow)]
  // (identical lane->element map as the old A-layout, so construction unchanged)
  f16x8 qf[2][4];
#pragma unroll
  for (int mt = 0; mt < 2; ++mt) {
    const int row = qbase + wave * 32 + mt * 16 + l16;
    const float* qp = Q + ((size_t)bh * SEQ + row) * HDIM;
#pragma unroll
    for (int ks = 0; ks < 4; ++ks) {
      const float4* p4 = (const float4*)(qp + ks * 32 + quad * 8);
      float4 a = p4[0], c = p4[1];
      f16x8 f;
      f[0] = (_Float16)a.x; f[1] = (_Float16)a.y; f[2] = (_Float16)a.z; f[3] = (_Float16)a.w;
      f[4] = (_Float16)c.x; f[5] = (_Float16)c.y; f[6] = (_Float16)c.z; f[7] = (_Float16)c.w;
      qf[mt][ks] = f;
    }
  }

  floatx4 o_acc[2][8];
#pragma unroll
  for (int mt = 0; mt < 2; ++mt)
#pragma unroll
    for (int n = 0; n < 8; ++n) o_acc[mt][n] = (floatx4){0.f, 0.f, 0.f, 0.f};
  float m_run[2] = {-INFINITY, -INFINITY};   // per-lane: qrow = mt*16 + l16
  float l_run[2] = {0.0f, 0.0f};

  const char* kg = (const char*)Kp + (size_t)bh * NKT * TILE_BYTES;
  const char* vg = (const char*)Vt + (size_t)bh * NKT * TILE_BYTES;
  const unsigned int* bits_p = bits + ((size_t)pat * SEQ + qbase) * (SEQ / 32);

  for (int kt = 0; kt < NKT; ++kt) {
    __syncthreads();  // previous iter's LDS reads done before restage
    {
      const char* kgt = kg + (size_t)kt * TILE_BYTES + wave * 1024 + lane * 16;
      const char* vgt = vg + (size_t)kt * TILE_BYTES + wave * 1024 + lane * 16;
      char* kl = kv_raw + wave * 1024;
      char* vl = kv_raw + TILE_BYTES + wave * 1024;
#pragma unroll
      for (int i = 0; i < 4; ++i) {
        __builtin_amdgcn_global_load_lds((gvoid_t*)(kgt + i * 4096),
                                         (lvoid_t*)(kl + i * 4096), 16, 0, 0);
        __builtin_amdgcn_global_load_lds((gvoid_t*)(vgt + i * 4096),
                                         (lvoid_t*)(vl + i * 4096), 16, 0, 0);
      }
      int mr = tid >> 1, mw = tid & 1;
      maskw[mr][mw] = bits_p[(size_t)mr * (SEQ / 32) + kt * 2 + mw];
    }
    __syncthreads();  // compiler drains vmcnt+lgkmcnt before s_barrier

    // ---- S^T = K @ Q^T : sf[t][mt], C-layout row = kcol-in-tile, col = qrow ----
    floatx4 sf[4][2];
#pragma unroll
    for (int t = 0; t < 4; ++t)
#pragma unroll
      for (int mt = 0; mt < 2; ++mt) sf[t][mt] = (floatx4){0.f, 0.f, 0.f, 0.f};
    __builtin_amdgcn_s_setprio(1);
#pragma unroll
    for (int t = 0; t < 4; ++t) {
      const char* krow = kv_raw + ((t * 16 + l16) << 8);
#pragma unroll
      for (int ks = 0; ks < 4; ++ks) {
        f16x8 kf = *(const f16x8*)(krow + ((((ks << 2) | quad) ^ swz) << 4));
#pragma unroll
        for (int mt = 0; mt < 2; ++mt)
          sf[t][mt] = __builtin_amdgcn_mfma_f32_16x16x32_f16(kf, qf[mt][ks], sf[t][mt], 0, 0, 0);
      }
    }
    __builtin_amdgcn_s_setprio(0);

    // ---- mask (multiplicative) + online softmax, lane-local row = l16 ----
    f16x4 hq[4][2];          // quantized P, per (kcol-tile, mt)
    float alpha[2];
#pragma unroll
    for (int mt = 0; mt < 2; ++mt) {
      const int rl = wave * 32 + mt * 16 + l16;
      const unsigned w0 = maskw[rl][0], w1 = maskw[rl][1];
#pragma unroll
      for (int t = 0; t < 4; ++t) {
        const unsigned wd = (t & 2) ? w1 : w0;
        const int base = ((t & 1) << 4) + (quad << 2);  // kcol&31 = (t&1)*16+quad*4+r
#pragma unroll
        for (int r = 0; r < 4; ++r) {
          float s = sf[t][mt][r];
          sf[t][mt][r] = ((wd >> (base + r)) & 1u) ? s * SCL : 0.0f;
        }
      }
      float mx = sf[0][mt][0];
#pragma unroll
      for (int t = 0; t < 4; ++t)
#pragma unroll
        for (int r = 0; r < 4; ++r) mx = fmaxf(mx, sf[t][mt][r]);
      mx = fmaxf(mx, __shfl_xor(mx, 16));
      mx = fmaxf(mx, __shfl_xor(mx, 32));
      const float m_old = m_run[mt];
      const float m_new = fmaxf(m_old, mx);
      const float a = exp2f(m_old - m_new);   // first iter: exp2(-inf)=0
      alpha[mt] = a;
      m_run[mt] = m_new;
      float ps = 0.0f;
#pragma unroll
      for (int t = 0; t < 4; ++t) {
#pragma unroll
        for (int r = 0; r < 4; ++r) {
          float p = exp2f(sf[t][mt][r] - m_new);
          if (p < P_MIN) p = 0.0f;            // stay out of fp16 subnormals
          _Float16 hh = (_Float16)p;          // quantize FIRST...
          hq[t][mt][r] = hh;
          ps += (float)hh;                    // ...then sum: l matches MFMA weights
        }
      }
      ps += __shfl_xor(ps, 16);
      ps += __shfl_xor(ps, 32);
      l_run[mt] = l_run[mt] * a + ps;
    }

    // ---- rescale O (alpha lives at lane l16=qrow; C-rows need quad*4+r) ----
#pragma unroll
    for (int mt = 0; mt < 2; ++mt) {
#pragma unroll
      for (int r = 0; r < 4; ++r) {
        const float ac = __shfl(alpha[mt], (quad << 2) | r, 16);
#pragma unroll
        for (int n = 0; n < 8; ++n) o_acc[mt][n][r] *= ac;
      }
    }

    // ---- P: C->A layout fully in-register ----
    // Lane keeps its own tile T=(quad>>1)*2+ks (slots j<4) and receives the
    // xor-32 partner's values of the SAME tile (slots j>=4). kc-slot mapping
    // is baked into prep_vt, so PV's A and B operands agree.
    __builtin_amdgcn_s_setprio(1);
#pragma unroll
    for (int ks = 0; ks < 2; ++ks) {
      f16x8 pa[2];
#pragma unroll
      for (int mt = 0; mt < 2; ++mt) {
        f16x4 hk = (quad & 2) ? hq[ks + 2][mt] : hq[ks][mt];   // keep: own consumed tile
        f16x4 hs = (quad & 2) ? hq[ks][mt] : hq[ks + 2][mt];   // send: partner's tile
        union { f16x4 v; unsigned u[2]; } K_, S_;
        K_.v = hk; S_.v = hs;
        unsigned p0 = (unsigned)__shfl_xor((int)S_.u[0], 32);
        unsigned p1 = (unsigned)__shfl_xor((int)S_.u[1], 32);
        union { unsigned u[4]; f16x8 v; } P_;
        P_.u[0] = K_.u[0]; P_.u[1] = K_.u[1]; P_.u[2] = p0; P_.u[3] = p1;
        pa[mt] = P_.v;
      }
#pragma unroll
      for (int nt = 0; nt < 8; ++nt) {
        const char* vrow = kv_raw + TILE_BYTES + ((nt * 16 + l16) << 7);
        f16x8 vb = *(const f16x8*)(vrow + ((((ks << 2) | quad) ^ swz) << 4));
#pragma unroll
        for (int mt = 0; mt < 2; ++mt)
          o_acc[mt][nt] = __builtin_amdgcn_mfma_f32_16x16x32_f16(pa[mt], vb, o_acc[mt][nt], 0, 0, 0);
      }
    }
    __builtin_amdgcn_s_setprio(0);
  }

  // ---- epilogue: O / l (l lives at lane l16=qrow; broadcast to C-rows) ----
#pragma unroll
  for (int mt = 0; mt < 2; ++mt) {
#pragma unroll
    for (int r = 0; r < 4; ++r) {
      const float lv = __shfl(l_run[mt], (quad << 2) | r, 16);
      const float inv = 1.0f / lv;
      const int row = qbase + wave * 32 + mt * 16 + quad * 4 + r;
      float* og = out + ((size_t)bh * SEQ + row) * HDIM + l16;
#pragma unroll
      for (int n = 0; n < 8; ++n) og[n * 16] = o_acc[mt][n][r] * inv;
    }
  }
}

extern "C" void kernel_launch(void* const* d_in, const int* in_sizes, int n_in,
                              void* d_out, int out_size, void* d_ws, size_t ws_size,
                              hipStream_t stream) {
  const float* Q  = (const float*)d_in[0];
  const float* K  = (const float*)d_in[1];
  const float* V  = (const float*)d_in[2];
  const float* pm = (const float*)d_in[3];
  const float* w1 = (const float*)d_in[4];
  const float* b1 = (const float*)d_in[5];
  const float* w2 = (const float*)d_in[6];
  const float* b2 = (const float*)d_in[7];
  float* out = (float*)d_out;

  // workspace layout (16B-aligned):
  //   [0,256)            pat_idx (16 ints)
  //   [256,512)          used-pattern flags (4 ints)
  //   [4096, +2MB)       mask bit words
  //   [+0, +32MB)        Kp fp16 swizzled tiles
  //   [+32MB, +64MB)     Vt fp16 transposed swizzled tiles
  int* pat_idx = (int*)d_ws;
  int* used = (int*)((char*)d_ws + 256);
  unsigned int* bits = (unsigned int*)((char*)d_ws + 4096);
  _Float16* Kp = (_Float16*)((char*)d_ws + 4096 + 2097152);
  _Float16* Vt = (_Float16*)((char*)d_ws + 4096 + 2097152 + 33554432);

  sel_kernel<<<1, 64, 0, stream>>>(w1, b1, w2, b2, pat_idx, used);
  bin_kernel<<<(NPAT * SEQ * (SEQ / 32)) / 256, 256, 0, stream>>>(pm, bits, used);
  prep_k<<<(BATCH * NHEADS * NKT * 1024) / 256, 256, 0, stream>>>(K, Kp);
  prep_vt<<<BATCH * NHEADS * NKT, 256, 0, stream>>>(V, Vt);
  flash_kernel<<<NBLOCKS, NTHREADS, 0, stream>>>(Q, Kp, Vt, bits, pat_idx, out);
}

// Round 4
// 479.303 us; speedup vs baseline: 2.1385x; 1.0969x over previous
//
#include <hip/hip_runtime.h>
#include <hip/hip_bf16.h>
#include <math.h>

#define BATCH 4
#define NHEADS 16
#define SEQ 2048
#define HDIM 128
#define NPAT 4

#define BM 128
#define BN 64
#define NTHREADS 256
#define NKT (SEQ / BN)          // 32 kv-tiles per (b,h)
#define TILE_BYTES 16384        // K tile: 64 rows x 256B ; V^T tile: 128 rows x 128B
#define NBLOCKS (BATCH * NHEADS * (SEQ / BM))   // 1024

typedef _Float16 f16x8 __attribute__((ext_vector_type(8)));
typedef _Float16 f16x4 __attribute__((ext_vector_type(4)));
typedef float floatx4 __attribute__((ext_vector_type(4)));

typedef const __attribute__((address_space(1))) void gvoid_t;
typedef __attribute__((address_space(3))) void lvoid_t;

// raw v_exp_f32 (exp2). OCML exp2f == v_exp_f32 + subnormal-result fixup; our
// P_MIN clamp (2^-14) makes the fixup unobservable -> bit-identical outcomes.
#if __has_builtin(__builtin_amdgcn_exp2f)
#define EXP2(x) __builtin_amdgcn_exp2f(x)
#else
#define EXP2(x) exp2f(x)
#endif

// ---------------- selector: per-head pattern argmax (+ used-pattern flags) ----
__global__ void sel_kernel(const float* __restrict__ w1, const float* __restrict__ b1,
                           const float* __restrict__ w2, const float* __restrict__ b2,
                           int* __restrict__ pat_idx, int* __restrict__ used) {
  int h = threadIdx.x;
  if (h < NPAT) used[h] = 0;
  __syncthreads();
  if (h >= NHEADS) return;
  float f0 = 1.0f;               // S / MAX_SEQ_LEN = 2048/2048
  float f1 = (float)h / 12.0f;
  float f2 = 0.5f;
  float acc[NPAT] = {b2[0], b2[1], b2[2], b2[3]};
  for (int j = 0; j < 32; ++j) {
    float hj = f0 * w1[j] + f1 * w1[32 + j] + f2 * w1[64 + j] + b1[j];
    hj = fmaxf(hj, 0.0f);
    for (int p = 0; p < NPAT; ++p) acc[p] += hj * w2[j * NPAT + p];
  }
  int best = 0;
  float bv = acc[0];
  for (int p = 1; p < NPAT; ++p) {
    if (acc[p] > bv) { bv = acc[p]; best = p; }   // strict > : first-max like jnp.argmax
  }
  pat_idx[h] = best;
  atomicOr(&used[best], 1);
}

// ---------------- binarize pattern masks to bit words ----------------
// Reference does sigmoid(x) > 0.5 IN FP32; exact-rounding window only matters
// for |x| < ~1e-5. CRITICAL: the slow path must NOT be if-converted (it was:
// the side-effect-free f64 exp was speculated for ALL 16.7M elements, ~150us).
// __noinline__ forces a call (cannot be speculated); outer __ballot guard makes
// the common case a wave-uniform skip. Bit-exact vs previous version.
__device__ __attribute__((noinline)) bool sig_gt_half_slow(float x) {
  float t = (float)exp(-(double)x);   // correctly-rounded fp32 exp(-x)
  float s = 1.0f / (1.0f + t);        // fp32 IEEE add + div
  return s > 0.5f;
}

__global__ void bin_kernel(const float* __restrict__ pm, unsigned int* __restrict__ bits,
                           const int* __restrict__ used) {
  int pat = blockIdx.x >> 9;                      // 512 blocks per pattern
  if (!used[pat]) return;
  int t = blockIdx.x * blockDim.x + threadIdx.x;  // one 32-col word per thread
  const float4* s4 = (const float4*)(pm + (size_t)t * 32);
  unsigned int w = 0;
  bool anyneed = false;
#pragma unroll
  for (int i = 0; i < 8; ++i) {
    float4 v = s4[i];
    float e[4] = {v.x, v.y, v.z, v.w};
#pragma unroll
    for (int j = 0; j < 4; ++j) {
      anyneed |= (fabsf(e[j]) < 1e-5f);
      w |= ((e[j] > 0.0f) ? 1u : 0u) << (i * 4 + j);
    }
  }
  if (__ballot(anyneed)) {        // wave-uniform guard: slow re-walk is rare
    if (anyneed) {                // divergent; calls are exec-masked, not speculated
      w = 0;
#pragma unroll 1
      for (int i = 0; i < 8; ++i) {
        float4 v = s4[i];
        float e[4] = {v.x, v.y, v.z, v.w};
        for (int j = 0; j < 4; ++j) {
          bool b = (fabsf(e[j]) < 1e-5f) ? sig_gt_half_slow(e[j]) : (e[j] > 0.0f);
          w |= (b ? 1u : 0u) << (i * 4 + j);
        }
      }
    }
  }
  bits[t] = w;
}

// ---------------- preprocess K: fp32 -> fp16 swizzled tiles ----------------
// Kp tile layout (16KB per (bh,kt)): byte o holds K[tile*64 + r][c] fp16 where
// r = o>>8, c = ((o&255) ^ ((r&7)<<4)) >> 1.  flash stages this linearly via
// global_load_lds and reads fragments at byte r*256 + (colbyte ^ ((r&7)<<4))
// -> conflict-free ds_read_b128.
__global__ __launch_bounds__(256) void prep_k(const float* __restrict__ K,
                                              _Float16* __restrict__ Kp) {
  size_t q0 = ((size_t)blockIdx.x * 256 + threadIdx.x) * 16;  // output byte
  int tile = (int)(q0 >> 14);
  int p = (int)(q0 & 16383);
  int r = p >> 8;
  int cb = (p & 255) ^ ((r & 7) << 4);
  const float* src = K + ((size_t)tile * 64 + r) * HDIM + (cb >> 1);
  float4 a = ((const float4*)src)[0];
  float4 b = ((const float4*)src)[1];
  f16x8 f;
  f[0] = (_Float16)a.x; f[1] = (_Float16)a.y; f[2] = (_Float16)a.z; f[3] = (_Float16)a.w;
  f[4] = (_Float16)b.x; f[5] = (_Float16)b.y; f[6] = (_Float16)b.z; f[7] = (_Float16)b.w;
  *(f16x8*)((char*)Kp + q0) = f;
}

// ---------------- preprocess V: LDS-transposed fp16 tiles -------------------
// Vt tile (16KB per (bh,kt)) = V^T [d=128][kc-slot], both sides coalesced via
// an LDS tile transpose. kc-slot ordering bakes BOTH the XOR-16B swizzle and
// the in-register P-exchange permutation used by flash's PV step:
//   chunk c' at row d holds logical chunk clog = c' ^ (d&7); q=clog&3, ks=clog>>2
//   slot j in chunk -> kc = ((q>>1)*2+ks)*16 + (j<4 ? q : q^2)*4 + (j&3)
__global__ __launch_bounds__(256) void prep_vt(const float* __restrict__ V,
                                               _Float16* __restrict__ Vt) {
  __shared__ _Float16 tile[64][140];   // pitch 140 f16 = 280B (8B-aligned, bank-spread)
  const int t = threadIdx.x;
  const float* vsrc = V + (size_t)blockIdx.x * 64 * HDIM;
#pragma unroll
  for (int i = 0; i < 8; ++i) {
    int idx = i * 256 + t;             // 2048 float4 chunks: row kc, 32 chunks/row
    int kc = idx >> 5, c4 = idx & 31;
    float4 v = ((const float4*)(vsrc + kc * HDIM))[c4];
    f16x4 f;
    f[0] = (_Float16)v.x; f[1] = (_Float16)v.y; f[2] = (_Float16)v.z; f[3] = (_Float16)v.w;
    *(f16x4*)&tile[kc][c4 * 4] = f;
  }
  __syncthreads();
  char* dst = (char*)Vt + (size_t)blockIdx.x * TILE_BYTES;
#pragma unroll
  for (int i = 0; i < 4; ++i) {
    int p = (i * 256 + t) * 16;        // output byte in tile
    int d = p >> 7;
    int cp = (p & 127) >> 4;
    int clog = cp ^ (d & 7);
    int q = clog & 3, ks = clog >> 2;
    int T16 = ((q >> 1) * 2 + ks) << 4;
    f16x8 f;
#pragma unroll
    for (int j = 0; j < 8; ++j) {
      int qsel = (j < 4) ? q : (q ^ 2);
      int kc = T16 + qsel * 4 + (j & 3);
      f[j] = tile[kc][d];
    }
    *(f16x8*)(dst + p) = f;
  }
}

// ---------------- flash attention with multiplicative binary mask ----------------
// 2-phase pipelined: double-buffered K/V/mask tiles staged by global_load_lds;
// prefetch of tile t+1 issued BEFORE computing tile t; ONE barrier per iter
// (its implicit vmcnt(0) lands after ~2000cy of compute -> latency hidden).
// THR=0 defer-max: when the running max doesn't grow (wave-uniform), the
// rescale pass is exp2(0)=1.0 multiplies -> skip it. Bit-exact.
__global__ __launch_bounds__(NTHREADS, 2) void flash_kernel(
    const float* __restrict__ Q, const _Float16* __restrict__ Kp,
    const _Float16* __restrict__ Vt, const unsigned int* __restrict__ bits,
    const int* __restrict__ pat_idx, float* __restrict__ out) {
  __shared__ alignas(16) char kv_raw[2][2 * TILE_BYTES];  // [buf][K@0 | V^T@16384]
  __shared__ unsigned int maskw[2][BM][2];

  const int tid = threadIdx.x;
  const int wave = tid >> 6;
  const int lane = tid & 63;
  const int l16 = lane & 15;
  const int quad = lane >> 4;
  const int swz = l16 & 7;

  // bijective XCD chunk swizzle
  int bid = (int)blockIdx.x;
  bid = (bid & 7) * (NBLOCKS / 8) + (bid >> 3);
  const int bh = bid >> 4;       // 0..63 = b*16+h
  const int qt = bid & 15;
  const int h = bh & (NHEADS - 1);
  const int qbase = qt * BM;
  const int pat = pat_idx[h];

  const float SCL = 0.08838834764831845f * 1.4426950408889634f;  // rsqrt(128)*log2(e)
  const float P_MIN = 6.103515625e-05f;  // 2^-14: fp16 normal floor; below -> 0

  const unsigned int* bits_p = bits + ((size_t)pat * SEQ + qbase) * (SEQ / 32);
  // per-lane staging bases (hoisted)
  const char* kgbase = (const char*)Kp + (size_t)bh * NKT * TILE_BYTES + wave * 1024 + lane * 16;
  const char* vgbase = (const char*)Vt + (size_t)bh * NKT * TILE_BYTES + wave * 1024 + lane * 16;
  const unsigned int* mgbase = bits_p + (size_t)(wave * 32 + (lane >> 1)) * (SEQ / 32) + (lane & 1);

  auto stage = [&](int nb, int kt) {
    const char* kgt = kgbase + (size_t)kt * TILE_BYTES;
    const char* vgt = vgbase + (size_t)kt * TILE_BYTES;
    char* kl = &kv_raw[nb][0] + wave * 1024;
    char* vl = &kv_raw[nb][TILE_BYTES] + wave * 1024;
#pragma unroll
    for (int i = 0; i < 4; ++i) {
      __builtin_amdgcn_global_load_lds((gvoid_t*)(kgt + i * 4096),
                                       (lvoid_t*)(kl + i * 4096), 16, 0, 0);
      __builtin_amdgcn_global_load_lds((gvoid_t*)(vgt + i * 4096),
                                       (lvoid_t*)(vl + i * 4096), 16, 0, 0);
    }
    // mask words: rows wave*32..wave*32+31, 2 words each -> lane*4 linear dest
    __builtin_amdgcn_global_load_lds((gvoid_t*)(mgbase + 2 * kt),
                                     (lvoid_t*)&maskw[nb][wave * 32][0], 4, 0, 0);
  };

  // prologue: stage tile 0 (DMA in flight while we build Q fragments)
  stage(0, 0);

  // Q fragments: B-operand of swapped QK^T, B[k=quad*8+j (d)][n=l16 (qrow)]
  f16x8 qf[2][4];
#pragma unroll
  for (int mt = 0; mt < 2; ++mt) {
    const int row = qbase + wave * 32 + mt * 16 + l16;
    const float* qp = Q + ((size_t)bh * SEQ + row) * HDIM;
#pragma unroll
    for (int ks = 0; ks < 4; ++ks) {
      const float4* p4 = (const float4*)(qp + ks * 32 + quad * 8);
      float4 a = p4[0], c = p4[1];
      f16x8 f;
      f[0] = (_Float16)a.x; f[1] = (_Float16)a.y; f[2] = (_Float16)a.z; f[3] = (_Float16)a.w;
      f[4] = (_Float16)c.x; f[5] = (_Float16)c.y; f[6] = (_Float16)c.z; f[7] = (_Float16)c.w;
      qf[mt][ks] = f;
    }
  }

  floatx4 o_acc[2][8];
#pragma unroll
  for (int mt = 0; mt < 2; ++mt)
#pragma unroll
    for (int n = 0; n < 8; ++n) o_acc[mt][n] = (floatx4){0.f, 0.f, 0.f, 0.f};
  float m_run[2] = {-INFINITY, -INFINITY};   // per-lane: qrow = mt*16 + l16
  float l_run[2] = {0.0f, 0.0f};

  __syncthreads();   // tile 0 resident
  int cur = 0;

  for (int kt = 0; kt < NKT; ++kt) {
    // prefetch next tile into the other buffer (drained at end-of-iter barrier)
    if (kt + 1 < NKT) stage(cur ^ 1, kt + 1);

    const char* kbuf = &kv_raw[cur][0];
    const char* vbuf = &kv_raw[cur][TILE_BYTES];

    // ---- S^T = K @ Q^T : sf[t][mt], C-layout row = kcol-in-tile, col = qrow ----
    floatx4 sf[4][2];
#pragma unroll
    for (int t = 0; t < 4; ++t)
#pragma unroll
      for (int mt = 0; mt < 2; ++mt) sf[t][mt] = (floatx4){0.f, 0.f, 0.f, 0.f};
    __builtin_amdgcn_s_setprio(1);
#pragma unroll
    for (int t = 0; t < 4; ++t) {
      const char* krow = kbuf + ((t * 16 + l16) << 8);
#pragma unroll
      for (int ks = 0; ks < 4; ++ks) {
        f16x8 kf = *(const f16x8*)(krow + ((((ks << 2) | quad) ^ swz) << 4));
#pragma unroll
        for (int mt = 0; mt < 2; ++mt)
          sf[t][mt] = __builtin_amdgcn_mfma_f32_16x16x32_f16(kf, qf[mt][ks], sf[t][mt], 0, 0, 0);
      }
    }
    __builtin_amdgcn_s_setprio(0);

    // ---- mask (multiplicative) + row max, lane-local row = l16 ----
#pragma unroll
    for (int mt = 0; mt < 2; ++mt) {
      const int rl = wave * 32 + mt * 16 + l16;
      const unsigned w0 = maskw[cur][rl][0], w1 = maskw[cur][rl][1];
#pragma unroll
      for (int t = 0; t < 4; ++t) {
        const unsigned wd = (t & 2) ? w1 : w0;
        const int base = ((t & 1) << 4) + (quad << 2);  // kcol&31 = (t&1)*16+quad*4+r
#pragma unroll
        for (int r = 0; r < 4; ++r) {
          float s = sf[t][mt][r];
          sf[t][mt][r] = ((wd >> (base + r)) & 1u) ? s * SCL : 0.0f;
        }
      }
    }
    float mx0 = sf[0][0][0], mx1 = sf[0][1][0];
#pragma unroll
    for (int t = 0; t < 4; ++t)
#pragma unroll
      for (int r = 0; r < 4; ++r) {
        mx0 = fmaxf(mx0, sf[t][0][r]);
        mx1 = fmaxf(mx1, sf[t][1][r]);
      }
    mx0 = fmaxf(mx0, __shfl_xor(mx0, 16));
    mx0 = fmaxf(mx0, __shfl_xor(mx0, 32));
    mx1 = fmaxf(mx1, __shfl_xor(mx1, 16));
    mx1 = fmaxf(mx1, __shfl_xor(mx1, 32));

    // ---- THR=0 defer-max: skip the exp2(0)=1.0 rescale when max unchanged ----
    if (!__all((mx0 <= m_run[0]) && (mx1 <= m_run[1]))) {
      float alpha[2];
      const float mn0 = fmaxf(m_run[0], mx0);
      const float mn1 = fmaxf(m_run[1], mx1);
      alpha[0] = EXP2(m_run[0] - mn0);   // first iter: exp2(-inf)=0
      alpha[1] = EXP2(m_run[1] - mn1);
      m_run[0] = mn0; m_run[1] = mn1;
      l_run[0] *= alpha[0]; l_run[1] *= alpha[1];
#pragma unroll
      for (int mt = 0; mt < 2; ++mt) {
#pragma unroll
        for (int r = 0; r < 4; ++r) {
          const float ac = __shfl(alpha[mt], (quad << 2) | r, 16);
#pragma unroll
          for (int n = 0; n < 8; ++n) o_acc[mt][n][r] *= ac;
        }
      }
    }

    // ---- P = exp2(S - m), quantize-first, row sum ----
    f16x4 hq[4][2];          // quantized P, per (kcol-tile, mt)
#pragma unroll
    for (int mt = 0; mt < 2; ++mt) {
      const float mrow = m_run[mt];
      float ps = 0.0f;
#pragma unroll
      for (int t = 0; t < 4; ++t) {
#pragma unroll
        for (int r = 0; r < 4; ++r) {
          float p = EXP2(sf[t][mt][r] - mrow);
          if (p < P_MIN) p = 0.0f;            // stay out of fp16 subnormals
          _Float16 hh = (_Float16)p;          // quantize FIRST...
          hq[t][mt][r] = hh;
          ps += (float)hh;                    // ...then sum: l matches MFMA weights
        }
      }
      ps += __shfl_xor(ps, 16);
      ps += __shfl_xor(ps, 32);
      l_run[mt] += ps;
    }

    // ---- P: C->A layout fully in-register ----
    __builtin_amdgcn_s_setprio(1);
#pragma unroll
    for (int ks = 0; ks < 2; ++ks) {
      f16x8 pa[2];
#pragma unroll
      for (int mt = 0; mt < 2; ++mt) {
        f16x4 hk = (quad & 2) ? hq[ks + 2][mt] : hq[ks][mt];   // keep: own consumed tile
        f16x4 hs = (quad & 2) ? hq[ks][mt] : hq[ks + 2][mt];   // send: partner's tile
        union { f16x4 v; unsigned u[2]; } K_, S_;
        K_.v = hk; S_.v = hs;
        unsigned p0 = (unsigned)__shfl_xor((int)S_.u[0], 32);
        unsigned p1 = (unsigned)__shfl_xor((int)S_.u[1], 32);
        union { unsigned u[4]; f16x8 v; } P_;
        P_.u[0] = K_.u[0]; P_.u[1] = K_.u[1]; P_.u[2] = p0; P_.u[3] = p1;
        pa[mt] = P_.v;
      }
#pragma unroll
      for (int nt = 0; nt < 8; ++nt) {
        const char* vrow = vbuf + ((nt * 16 + l16) << 7);
        f16x8 vb = *(const f16x8*)(vrow + ((((ks << 2) | quad) ^ swz) << 4));
#pragma unroll
        for (int mt = 0; mt < 2; ++mt)
          o_acc[mt][nt] = __builtin_amdgcn_mfma_f32_16x16x32_f16(pa[mt], vb, o_acc[mt][nt], 0, 0, 0);
      }
    }
    __builtin_amdgcn_s_setprio(0);

    __syncthreads();   // drains this iter's prefetch + joins LDS reads; buffers flip
    cur ^= 1;
  }

  // ---- epilogue: O / l (l lives at lane l16=qrow; broadcast to C-rows) ----
#pragma unroll
  for (int mt = 0; mt < 2; ++mt) {
#pragma unroll
    for (int r = 0; r < 4; ++r) {
      const float lv = __shfl(l_run[mt], (quad << 2) | r, 16);
      const float inv = 1.0f / lv;
      const int row = qbase + wave * 32 + mt * 16 + quad * 4 + r;
      float* og = out + ((size_t)bh * SEQ + row) * HDIM + l16;
#pragma unroll
      for (int n = 0; n < 8; ++n) og[n * 16] = o_acc[mt][n][r] * inv;
    }
  }
}

extern "C" void kernel_launch(void* const* d_in, const int* in_sizes, int n_in,
                              void* d_out, int out_size, void* d_ws, size_t ws_size,
                              hipStream_t stream) {
  const float* Q  = (const float*)d_in[0];
  const float* K  = (const float*)d_in[1];
  const float* V  = (const float*)d_in[2];
  const float* pm = (const float*)d_in[3];
  const float* w1 = (const float*)d_in[4];
  const float* b1 = (const float*)d_in[5];
  const float* w2 = (const float*)d_in[6];
  const float* b2 = (const float*)d_in[7];
  float* out = (float*)d_out;

  // workspace layout (16B-aligned):
  //   [0,256)            pat_idx (16 ints)
  //   [256,512)          used-pattern flags (4 ints)
  //   [4096, +2MB)       mask bit words
  //   [+0, +32MB)        Kp fp16 swizzled tiles
  //   [+32MB, +64MB)     Vt fp16 transposed swizzled tiles
  int* pat_idx = (int*)d_ws;
  int* used = (int*)((char*)d_ws + 256);
  unsigned int* bits = (unsigned int*)((char*)d_ws + 4096);
  _Float16* Kp = (_Float16*)((char*)d_ws + 4096 + 2097152);
  _Float16* Vt = (_Float16*)((char*)d_ws + 4096 + 2097152 + 33554432);

  sel_kernel<<<1, 64, 0, stream>>>(w1, b1, w2, b2, pat_idx, used);
  bin_kernel<<<(NPAT * SEQ * (SEQ / 32)) / 256, 256, 0, stream>>>(pm, bits, used);
  prep_k<<<(BATCH * NHEADS * NKT * 1024) / 256, 256, 0, stream>>>(K, Kp);
  prep_vt<<<BATCH * NHEADS * NKT, 256, 0, stream>>>(V, Vt);
  flash_kernel<<<NBLOCKS, NTHREADS, 0, stream>>>(Q, Kp, Vt, bits, pat_idx, out);
}